// Round 6
// baseline (259.901 us; speedup 1.0000x reference)
//
#include <hip/hip_runtime.h>

typedef float f32x4 __attribute__((ext_vector_type(4)));
typedef short bf16x8 __attribute__((ext_vector_type(8)));
typedef unsigned short ushort_t;

#define NB 2
#define NC 64
#define ND 12
#define NH 256
#define NW 64
#define CSTRIDE (ND*NH*NW)   // 196608
#define QSZ_ELEMS (24*64*256*64)          // 25,165,824 bf16 elems per tensor
#define WS_NEED   ((size_t)3*QSZ_ELEMS*2) // 150,994,944 bytes

__device__ __forceinline__ ushort_t bf_round(float f){
    unsigned int u = __float_as_uint(f);
    return (ushort_t)((u + 0x7fffu + ((u >> 16) & 1u)) >> 16);   // RNE
}
__device__ __forceinline__ float bf_to_f(ushort_t s){ return __uint_as_float(((unsigned int)s) << 16); }

union U4S8 { uint4 u; bf16x8 s; };

// swizzled byte offsets: [R][64]-bf16 row-major, 8-elem (16B) chunks, chunk ^= row&7
__device__ __forceinline__ int row64_off(int r, int o){
    return r*128 + ((((o>>3) ^ (r&7)))<<4) + (o&7)*2;
}
__device__ __forceinline__ int row64_chunk(int r, int kchunk){
    return r*128 + (((kchunk ^ (r&7)))<<4);
}
// Vt: [64 c][256 g] bf16, rowbytes 512, 32 chunks, chunk ^= c&7
__device__ __forceinline__ int vt_off(int c, int g){
    return c*512 + ((((g>>3) ^ (c&7)))<<4) + (g&7)*2;
}
__device__ __forceinline__ int vt_chunk(int c, int gchunk){
    return c*512 + (((gchunk ^ (c&7)))<<4);
}

// weight frag: lane (hl,G) holds W[hl+16*ot][32m+8G .. +8] as bf16x8
__device__ __forceinline__ U4S8 wfrag_f(const float* W, int hl, int G, int ot, int m){
    const float* p2 = W + (hl + 16*ot)*NC + 32*m + 8*G;
    float4 f0 = *(const float4*)p2;
    float4 f1 = *(const float4*)(p2 + 4);
    U4S8 u; ushort_t* s = (ushort_t*)&u;
    s[0]=bf_round(f0.x); s[1]=bf_round(f0.y); s[2]=bf_round(f0.z); s[3]=bf_round(f0.w);
    s[4]=bf_round(f1.x); s[5]=bf_round(f1.y); s[6]=bf_round(f1.z); s[7]=bf_round(f1.w);
    return u;
}

// ===================== Kernel 1 (v4): QKV projection, single 32KB LDS, 4 blocks/CU ========
// block = (bd, h-tile of 4) covering all 64 w. Local row n = hh*64 + w (hh=n>>6).
// Round-4 proven data path (coalesced X loads -> LDS -> MFMA -> LDS bounce -> b128 ws
// stores); XL is reused as the bounce buffer after A-frags land in registers, halving
// LDS (64->32 KB) so occupancy doubles (2 -> 4 blocks/CU).
__global__ __launch_bounds__(256, 4) void k1_proj(
    const float* __restrict__ rep,
    const float* __restrict__ Wq, const float* __restrict__ bq,
    const float* __restrict__ Wk, const float* __restrict__ bk,
    const float* __restrict__ Wv, const float* __restrict__ bv,
    ushort_t* __restrict__ qws, ushort_t* __restrict__ kws, ushort_t* __restrict__ vws)
{
    __shared__ __align__(16) unsigned char XL[32768];   // X stage, then output bounce

    const int t = threadIdx.x, lane = t & 63, wid = t >> 6;
    const int G = lane >> 4, hl = lane & 15;
    const int blk = blockIdx.x;
    const int bd = blk >> 6;
    const int h0 = (blk & 63) * 4;
    const int d = bd % ND, b = bd / ND;
    const long dbase2 = (long)b*NC*CSTRIDE + (long)d*(NH*NW) + (long)h0*NW; // + c*CSTRIDE + n

    // ---- stage X tile: fully coalesced (per instr: 256 consecutive floats per c) ----
#pragma unroll
    for (int oct = 0; oct < 8; ++oct){
        float f[8];
#pragma unroll
        for (int j = 0; j < 8; ++j)
            f[j] = rep[dbase2 + (long)(8*oct + j)*CSTRIDE + t];
        U4S8 u; ushort_t* s = (ushort_t*)&u;
#pragma unroll
        for (int j = 0; j < 8; ++j) s[j] = bf_round(f[j]);
        *(uint4*)(XL + row64_chunk(t, oct)) = u.u;
    }
    __syncthreads();

    U4S8 xa[4][2];
#pragma unroll
    for (int nt = 0; nt < 4; ++nt)
#pragma unroll
        for (int m = 0; m < 2; ++m)
            xa[nt][m].u = *(const uint4*)(XL + row64_chunk(64*wid + 16*nt + hl, 4*m + G));
    __syncthreads();   // all waves done reading X -> XL free for bounce

    auto pass = [&](const float* W, const float* bias, float scale, ushort_t* dst){
        U4S8 bw[4][2];
        float bb[4];
#pragma unroll
        for (int ot = 0; ot < 4; ++ot){
            bw[ot][0] = wfrag_f(W, hl, G, ot, 0);
            bw[ot][1] = wfrag_f(W, hl, G, ot, 1);
            bb[ot] = bias[hl + 16*ot];
        }
        f32x4 acc[4][4];
#pragma unroll
        for (int nt = 0; nt < 4; ++nt)
#pragma unroll
            for (int ot = 0; ot < 4; ++ot){
                f32x4 a = {0.f,0.f,0.f,0.f};
                a = __builtin_amdgcn_mfma_f32_16x16x32_bf16(xa[nt][0].s, bw[ot][0].s, a, 0,0,0);
                a = __builtin_amdgcn_mfma_f32_16x16x32_bf16(xa[nt][1].s, bw[ot][1].s, a, 0,0,0);
#pragma unroll
                for (int r = 0; r < 4; ++r) a[r] = fmaxf(a[r] + bb[ot], 0.f) * scale;
                acc[nt][ot] = a;
            }
        // scatter D[n,o] -> bounce LDS
#pragma unroll
        for (int nt = 0; nt < 4; ++nt)
#pragma unroll
            for (int ot = 0; ot < 4; ++ot)
#pragma unroll
                for (int r = 0; r < 4; ++r){
                    int n = 64*wid + 16*nt + 4*G + r;
                    int o = hl + 16*ot;
                    *(ushort_t*)(XL + row64_off(n, o)) = bf_round(acc[nt][ot][r]);
                }
        __syncthreads();
        // full-line ws writes: chunk (n, c8); ws row = (bd*64 + w)*256 + h0 + hh
#pragma unroll
        for (int i = 0; i < 8; ++i){
            int g2 = i*256 + t; int n = g2 >> 3; int c8 = g2 & 7;
            uint4 u = *(const uint4*)(XL + row64_chunk(n, c8));
            long row_g = ((long)bd*64 + (n & 63))*256 + h0 + (n >> 6);
            *(uint4*)((unsigned char*)dst + row_g*128 + c8*16) = u;
        }
        __syncthreads();   // before next pass overwrites the bounce
    };
    pass(Wq, bq, 0.125f, qws);   // fold 1/sqrt(C)
    pass(Wk, bk, 1.0f,   kws);
    pass(Wv, bv, 1.0f,   vws);
}

// ===================== Kernel 2: attention per (bd,w), coalesced ws I/O =====================
__global__ __launch_bounds__(256, 2) void k2_attn(
    ushort_t* __restrict__ qws, const ushort_t* __restrict__ kws, const ushort_t* __restrict__ vws)
{
    __shared__ __align__(16) unsigned char smem[65536];
    unsigned char* KL = smem;          // K [256 g][64 c] row64 -> later O-bounce [h][c]
    unsigned char* VT = smem + 32768;  // Vt [64 c][256 g]

    const int t = threadIdx.x, lane = t & 63, wid = t >> 6;
    const int G = lane >> 4, hl = lane & 15;
    const int bdw = blockIdx.x;
    ushort_t* qslice = qws + (size_t)bdw*16384;          // [h][c], also O dst
    const unsigned char* kslice = (const unsigned char*)(kws + (size_t)bdw*16384);
    const unsigned char* vslice = (const unsigned char*)(vws + (size_t)bdw*16384);

    // ---- stage K (b128 direct) and V (transpose scatter) ----
#pragma unroll
    for (int i = 0; i < 8; ++i){
        int g2 = i*256 + t; int g = g2 >> 3; int c8 = g2 & 7;
        uint4 ku = *(const uint4*)(kslice + g2*16);
        *(uint4*)(KL + row64_chunk(g, c8)) = ku;
        U4S8 vu; vu.u = *(const uint4*)(vslice + g2*16);
#pragma unroll
        for (int j = 0; j < 8; ++j)
            *(ushort_t*)(VT + vt_off(8*c8 + j, g)) = (ushort_t)vu.s[j];
    }
    __syncthreads();

    // Q B-frags direct from global (plain [h][c] rows, octet 4m+G at byte (4m+G)*16)
    U4S8 qfr[4][2];
#pragma unroll
    for (int ht = 0; ht < 4; ++ht)
#pragma unroll
        for (int m = 0; m < 2; ++m)
            qfr[ht][m].u = *(const uint4*)((const unsigned char*)qslice
                              + (64*wid + 16*ht + hl)*128 + (4*m + G)*16);

    // ================= flash attention over g-tiles of 64 ================
    f32x4 oacc[4][4];
#pragma unroll
    for (int ct = 0; ct < 4; ++ct)
#pragma unroll
        for (int ht = 0; ht < 4; ++ht) oacc[ct][ht] = (f32x4){0.f,0.f,0.f,0.f};
    float m_run[4], l_run[4];
#pragma unroll
    for (int ht = 0; ht < 4; ++ht){ m_run[ht] = -1e30f; l_run[ht] = 0.f; }

    const int srcq0 = (16*((2*G    ) & 3) + hl)*4;
    const int srcq1 = (16*((2*G + 1) & 3) + hl)*4;

    for (int gb = 0; gb < NH; gb += 64){
        U4S8 kfr[4][2];
#pragma unroll
        for (int gt = 0; gt < 4; ++gt)
#pragma unroll
            for (int m = 0; m < 2; ++m)
                kfr[gt][m].u = *(const uint4*)(KL + row64_chunk(gb + 16*gt + hl, 4*m + G));

        f32x4 sacc[4][4];
#pragma unroll
        for (int gt = 0; gt < 4; ++gt)
#pragma unroll
            for (int ht = 0; ht < 4; ++ht){
                f32x4 a = {0.f,0.f,0.f,0.f};
                a = __builtin_amdgcn_mfma_f32_16x16x32_bf16(kfr[gt][0].s, qfr[ht][0].s, a, 0,0,0);
                a = __builtin_amdgcn_mfma_f32_16x16x32_bf16(kfr[gt][1].s, qfr[ht][1].s, a, 0,0,0);
                sacc[gt][ht] = a;
            }

        unsigned int pk[4][4][2];
#pragma unroll
        for (int ht = 0; ht < 4; ++ht){
            float cm = -1e30f;
#pragma unroll
            for (int gt = 0; gt < 4; ++gt)
#pragma unroll
                for (int r = 0; r < 4; ++r) cm = fmaxf(cm, sacc[gt][ht][r]);
            cm = fmaxf(cm, __shfl_xor(cm, 16));
            cm = fmaxf(cm, __shfl_xor(cm, 32));
            const float mn  = fmaxf(m_run[ht], cm);
            const float corr = __expf(m_run[ht] - mn);
            m_run[ht] = mn;
            float ls = 0.f;
#pragma unroll
            for (int gt = 0; gt < 4; ++gt){
                f32x4 s = sacc[gt][ht];
                float e0 = __expf(s[0]-mn), e1 = __expf(s[1]-mn);
                float e2 = __expf(s[2]-mn), e3 = __expf(s[3]-mn);
                ls += (e0+e1)+(e2+e3);
                pk[ht][gt][0] = (unsigned int)bf_round(e0) | ((unsigned int)bf_round(e1) << 16);
                pk[ht][gt][1] = (unsigned int)bf_round(e2) | ((unsigned int)bf_round(e3) << 16);
            }
            ls += __shfl_xor(ls, 16);
            ls += __shfl_xor(ls, 32);
            l_run[ht] = l_run[ht]*corr + ls;
#pragma unroll
            for (int ct = 0; ct < 4; ++ct)
#pragma unroll
                for (int r = 0; r < 4; ++r) oacc[ct][ht][r] *= corr;
        }

        U4S8 vfr[4][2];
#pragma unroll
        for (int ct = 0; ct < 4; ++ct)
#pragma unroll
            for (int m = 0; m < 2; ++m)
                vfr[ct][m].u = *(const uint4*)(VT + vt_chunk(16*ct + hl, (gb>>3) + 4*m + G));

#pragma unroll
        for (int m = 0; m < 2; ++m){
            U4S8 bfr[4];
#pragma unroll
            for (int ht = 0; ht < 4; ++ht){
                unsigned int wv[4];
#pragma unroll
                for (int jj = 0; jj < 4; ++jj){
                    const int src = (jj >> 1) ? srcq1 : srcq0;
                    const int p2  = jj & 1;
                    int rA = __builtin_amdgcn_ds_bpermute(src, (int)pk[ht][2*m  ][p2]);
                    int rB = __builtin_amdgcn_ds_bpermute(src, (int)pk[ht][2*m+1][p2]);
                    wv[jj] = (lane < 32) ? (unsigned int)rA : (unsigned int)rB;
                }
                bfr[ht].u = make_uint4(wv[0], wv[1], wv[2], wv[3]);
            }
#pragma unroll
            for (int ct = 0; ct < 4; ++ct)
#pragma unroll
                for (int ht = 0; ht < 4; ++ht)
                    oacc[ct][ht] = __builtin_amdgcn_mfma_f32_16x16x32_bf16(vfr[ct][m].s, bfr[ht].s, oacc[ct][ht], 0,0,0);
        }
    }

    // ---- epilogue: normalize, bounce O[h][c] through KL, coalesced write to qslice ----
    float invl[4];
#pragma unroll
    for (int ht = 0; ht < 4; ++ht) invl[ht] = 1.f / l_run[ht];

    __syncthreads();   // all waves done with KL/VT
#pragma unroll
    for (int ct = 0; ct < 4; ++ct)
#pragma unroll
        for (int ht = 0; ht < 4; ++ht)
#pragma unroll
            for (int r = 0; r < 4; ++r){
                int h = 64*wid + 16*ht + hl;
                int c = 16*ct + 4*G + r;
                *(ushort_t*)(KL + row64_off(h, c)) = bf_round(oacc[ct][ht][r] * invl[ht]);
            }
    __syncthreads();
#pragma unroll
    for (int i = 0; i < 8; ++i){
        int g2 = i*256 + t;
        uint4 u = *(const uint4*)(KL + row64_chunk(g2 >> 3, g2 & 7));
        *(uint4*)((unsigned char*)qslice + g2*16) = u;
    }
}

// ===================== Kernel 3: FC + ReLU + transpose-out, coalesced =====================
__global__ __launch_bounds__(256, 2) void k3_fc(
    const ushort_t* __restrict__ ows, const float* __restrict__ Wf, const float* __restrict__ bfc,
    float* __restrict__ out)
{
    __shared__ __align__(16) float YL[16384];   // [256 n][64 o], o swizzled, 64 KB

    const int t = threadIdx.x, lane = t & 63, wid = t >> 6;
    const int G = lane >> 4, hl = lane & 15;
    const int blk = blockIdx.x;
    const int bd = blk >> 6;
    const int h0 = (blk & 63) * 4;
    const int d = bd % ND, b = bd / ND;

    // A-frags: O rows (w = 16nt+hl, h = h0+wid), octet 4m+G
    U4S8 xa[4][2];
#pragma unroll
    for (int nt = 0; nt < 4; ++nt)
#pragma unroll
        for (int m = 0; m < 2; ++m){
            long row_g = ((long)bd*64 + (16*nt + hl))*256 + h0 + wid;
            xa[nt][m].u = *(const uint4*)((const unsigned char*)ows + row_g*128 + (4*m + G)*16);
        }

    U4S8 bw[4][2];
    float bb[4];
#pragma unroll
    for (int ot = 0; ot < 4; ++ot){
        bw[ot][0] = wfrag_f(Wf, hl, G, ot, 0);
        bw[ot][1] = wfrag_f(Wf, hl, G, ot, 1);
        bb[ot] = bfc[hl + 16*ot];
    }

    f32x4 acc[4][4];
#pragma unroll
    for (int nt = 0; nt < 4; ++nt)
#pragma unroll
        for (int ot = 0; ot < 4; ++ot){
            f32x4 a = {0.f,0.f,0.f,0.f};
            a = __builtin_amdgcn_mfma_f32_16x16x32_bf16(xa[nt][0].s, bw[ot][0].s, a, 0,0,0);
            a = __builtin_amdgcn_mfma_f32_16x16x32_bf16(xa[nt][1].s, bw[ot][1].s, a, 0,0,0);
#pragma unroll
            for (int r = 0; r < 4; ++r) a[r] = fmaxf(a[r] + bb[ot], 0.f);
            acc[nt][ot] = a;
        }

    // scatter Y[n][o] -> LDS (o ^= (n>>2)&31 swizzle)
#pragma unroll
    for (int nt = 0; nt < 4; ++nt)
#pragma unroll
        for (int ot = 0; ot < 4; ++ot)
#pragma unroll
            for (int r = 0; r < 4; ++r){
                int n = 64*wid + 16*nt + 4*G + r;
                int o = hl + 16*ot;
                YL[(n<<6) + (o ^ ((n>>2)&31))] = acc[nt][ot][r];
            }
    __syncthreads();

    // coalesced out writes: per instr one o, 1KB contiguous (4h x 64w)
    const long base3 = (long)b*NC*CSTRIDE + (long)d*(NH*NW) + (long)h0*NW;
#pragma unroll
    for (int i = 0; i < 16; ++i){
        int idx = i*1024 + t*4;
        int o = idx >> 8;
        int n0 = idx & 255;
        int osw = o ^ (t & 31);
        float4 v;
        v.x = YL[((n0+0)<<6) + osw];
        v.y = YL[((n0+1)<<6) + osw];
        v.z = YL[((n0+2)<<6) + osw];
        v.w = YL[((n0+3)<<6) + osw];
        *(float4*)(&out[base3 + (long)o*CSTRIDE + n0]) = v;
    }
}

// ===================== Fallback: round-3 fused kernel (proven) =====================
__global__ __launch_bounds__(256, 2) void sa_mfma(
    const float* __restrict__ rep,
    const float* __restrict__ Wq, const float* __restrict__ bq,
    const float* __restrict__ Wk, const float* __restrict__ bk,
    const float* __restrict__ Wv, const float* __restrict__ bv,
    const float* __restrict__ Wf, const float* __restrict__ bfc,
    float* __restrict__ out)
{
    __shared__ __align__(16) unsigned char smem[65536];
    unsigned char* BUFA = smem;
    unsigned char* BUFB = smem + 32768;

    const int t = threadIdx.x, lane = t & 63, wid = t >> 6;
    const int G = lane >> 4, hl = lane & 15;
    const int j = blockIdx.x;
    const int x = j & 7;
    const int p = j >> 3;
    const int group = ((p >> 6) << 3) + x;
    const int w = p & 63;
    const int d = group % ND;
    const int b = group / ND;
    const long base_bd = (long)b*(NC*CSTRIDE) + (long)d*(NH*NW) + w;

    {
        const int h = t;
        const long rbase = base_bd + (long)h*NW;
#pragma unroll
        for (int c8 = 0; c8 < 8; ++c8){
            U4S8 u;
            ushort_t* s = (ushort_t*)&u;
#pragma unroll
            for (int jj = 0; jj < 8; ++jj)
                s[jj] = bf_round(rep[rbase + (long)(c8*8 + jj)*CSTRIDE]);
            *(uint4*)(BUFB + row64_chunk(h, c8)) = u.u;
        }
    }
    U4S8 xafr[4][2];
#pragma unroll
    for (int ht = 0; ht < 4; ++ht)
#pragma unroll
        for (int m = 0; m < 2; ++m)
            xafr[ht][m].u = *(const uint4*)(BUFB + row64_chunk(64*wid + 16*ht + hl, 4*m + G));

    auto do_proj = [&](const float* W, const float* bias, float scale, f32x4 (&acc)[4][4]){
        U4S8 bw[4][2];
#pragma unroll
        for (int ot = 0; ot < 4; ++ot){ bw[ot][0] = wfrag_f(W, hl, G, ot, 0); bw[ot][1] = wfrag_f(W, hl, G, ot, 1); }
        float bb[4];
#pragma unroll
        for (int ot = 0; ot < 4; ++ot) bb[ot] = bias[hl + 16*ot];
#pragma unroll
        for (int ht = 0; ht < 4; ++ht)
#pragma unroll
            for (int ot = 0; ot < 4; ++ot){
                f32x4 a = {0.f, 0.f, 0.f, 0.f};
                a = __builtin_amdgcn_mfma_f32_16x16x32_bf16(xafr[ht][0].s, bw[ot][0].s, a, 0, 0, 0);
                a = __builtin_amdgcn_mfma_f32_16x16x32_bf16(xafr[ht][1].s, bw[ot][1].s, a, 0, 0, 0);
#pragma unroll
                for (int r = 0; r < 4; ++r) a[r] = fmaxf(a[r] + bb[ot], 0.f) * scale;
                acc[ht][ot] = a;
            }
    };

    {
        f32x4 qa[4][4];
        do_proj(Wq, bq, 0.125f, qa);
#pragma unroll
        for (int ht = 0; ht < 4; ++ht)
#pragma unroll
            for (int ot = 0; ot < 4; ++ot)
#pragma unroll
                for (int r = 0; r < 4; ++r){
                    int h = 64*wid + 16*ht + 4*G + r;
                    int o = hl + 16*ot;
                    *(ushort_t*)(BUFA + row64_off(h, o)) = bf_round(qa[ht][ot][r]);
                }
    }
    U4S8 qfr[4][2];
#pragma unroll
    for (int ht = 0; ht < 4; ++ht)
#pragma unroll
        for (int m = 0; m < 2; ++m)
            qfr[ht][m].u = *(const uint4*)(BUFA + row64_chunk(64*wid + 16*ht + hl, 4*m + G));

    {
        f32x4 ka[4][4];
        do_proj(Wk, bk, 1.0f, ka);
#pragma unroll
        for (int gt = 0; gt < 4; ++gt)
#pragma unroll
            for (int ot = 0; ot < 4; ++ot)
#pragma unroll
                for (int r = 0; r < 4; ++r){
                    int g = 64*wid + 16*gt + 4*G + r;
                    int o = hl + 16*ot;
                    *(ushort_t*)(BUFA + row64_off(g, o)) = bf_round(ka[gt][ot][r]);
                }
    }
    f32x4 va[4][4];
    do_proj(Wv, bv, 1.0f, va);
    __syncthreads();
#pragma unroll
    for (int gt = 0; gt < 4; ++gt)
#pragma unroll
        for (int ot = 0; ot < 4; ++ot)
#pragma unroll
            for (int r = 0; r < 4; ++r){
                int g = 64*wid + 16*gt + 4*G + r;
                int c = hl + 16*ot;
                *(ushort_t*)(BUFB + vt_off(c, g)) = bf_round(va[gt][ot][r]);
            }
    __syncthreads();

    f32x4 oacc[4][4];
#pragma unroll
    for (int ct = 0; ct < 4; ++ct)
#pragma unroll
        for (int ht = 0; ht < 4; ++ht) oacc[ct][ht] = (f32x4){0.f,0.f,0.f,0.f};
    float m_run[4], l_run[4];
#pragma unroll
    for (int ht = 0; ht < 4; ++ht){ m_run[ht] = -1e30f; l_run[ht] = 0.f; }

    const int srcq0 = (16*((2*G    ) & 3) + hl)*4;
    const int srcq1 = (16*((2*G + 1) & 3) + hl)*4;

    for (int gb = 0; gb < NH; gb += 64){
        U4S8 kfr[4][2];
#pragma unroll
        for (int gt = 0; gt < 4; ++gt)
#pragma unroll
            for (int m = 0; m < 2; ++m)
                kfr[gt][m].u = *(const uint4*)(BUFA + row64_chunk(gb + 16*gt + hl, 4*m + G));

        f32x4 sacc[4][4];
#pragma unroll
        for (int gt = 0; gt < 4; ++gt)
#pragma unroll
            for (int ht = 0; ht < 4; ++ht){
                f32x4 a = {0.f,0.f,0.f,0.f};
                a = __builtin_amdgcn_mfma_f32_16x16x32_bf16(kfr[gt][0].s, qfr[ht][0].s, a, 0,0,0);
                a = __builtin_amdgcn_mfma_f32_16x16x32_bf16(kfr[gt][1].s, qfr[ht][1].s, a, 0,0,0);
                sacc[gt][ht] = a;
            }

        unsigned int pk[4][4][2];
#pragma unroll
        for (int ht = 0; ht < 4; ++ht){
            float cm = -1e30f;
#pragma unroll
            for (int gt = 0; gt < 4; ++gt)
#pragma unroll
                for (int r = 0; r < 4; ++r) cm = fmaxf(cm, sacc[gt][ht][r]);
            cm = fmaxf(cm, __shfl_xor(cm, 16));
            cm = fmaxf(cm, __shfl_xor(cm, 32));
            const float mn  = fmaxf(m_run[ht], cm);
            const float corr = __expf(m_run[ht] - mn);
            m_run[ht] = mn;
            float ls = 0.f;
#pragma unroll
            for (int gt = 0; gt < 4; ++gt){
                f32x4 s = sacc[gt][ht];
                float e0 = __expf(s[0]-mn), e1 = __expf(s[1]-mn);
                float e2 = __expf(s[2]-mn), e3 = __expf(s[3]-mn);
                ls += (e0+e1)+(e2+e3);
                pk[ht][gt][0] = (unsigned int)bf_round(e0) | ((unsigned int)bf_round(e1) << 16);
                pk[ht][gt][1] = (unsigned int)bf_round(e2) | ((unsigned int)bf_round(e3) << 16);
            }
            ls += __shfl_xor(ls, 16);
            ls += __shfl_xor(ls, 32);
            l_run[ht] = l_run[ht]*corr + ls;
#pragma unroll
            for (int ct = 0; ct < 4; ++ct)
#pragma unroll
                for (int r = 0; r < 4; ++r) oacc[ct][ht][r] *= corr;
        }

        U4S8 vfr[4][2];
#pragma unroll
        for (int ct = 0; ct < 4; ++ct)
#pragma unroll
            for (int m = 0; m < 2; ++m)
                vfr[ct][m].u = *(const uint4*)(BUFB + vt_chunk(16*ct + hl, (gb>>3) + 4*m + G));

#pragma unroll
        for (int m = 0; m < 2; ++m){
            U4S8 bfr[4];
#pragma unroll
            for (int ht = 0; ht < 4; ++ht){
                unsigned int wv[4];
#pragma unroll
                for (int jj = 0; jj < 4; ++jj){
                    const int src = (jj >> 1) ? srcq1 : srcq0;
                    const int p2  = jj & 1;
                    int rA = __builtin_amdgcn_ds_bpermute(src, (int)pk[ht][2*m  ][p2]);
                    int rB = __builtin_amdgcn_ds_bpermute(src, (int)pk[ht][2*m+1][p2]);
                    wv[jj] = (lane < 32) ? (unsigned int)rA : (unsigned int)rB;
                }
                bfr[ht].u = make_uint4(wv[0], wv[1], wv[2], wv[3]);
            }
#pragma unroll
            for (int ct = 0; ct < 4; ++ct)
#pragma unroll
                for (int ht = 0; ht < 4; ++ht)
                    oacc[ct][ht] = __builtin_amdgcn_mfma_f32_16x16x32_bf16(vfr[ct][m].s, bfr[ht].s, oacc[ct][ht], 0,0,0);
        }
    }

    float invl[4];
#pragma unroll
    for (int ht = 0; ht < 4; ++ht) invl[ht] = 1.f / l_run[ht];
    __syncthreads();
#pragma unroll
    for (int ct = 0; ct < 4; ++ct)
#pragma unroll
        for (int ht = 0; ht < 4; ++ht)
#pragma unroll
            for (int r = 0; r < 4; ++r){
                float v = oacc[ct][ht][r] * invl[ht];
                ushort_t hi = bf_round(v);
                ushort_t lo = bf_round(v - bf_to_f(hi));
                int hrow = 64*wid + 16*ht + hl;
                int c = 16*ct + 4*G + r;
                *(ushort_t*)(BUFA + row64_off(hrow, c)) = hi;
                *(ushort_t*)(BUFB + row64_off(hrow, c)) = lo;
            }
    U4S8 bh[4][2], bl[4][2];
#pragma unroll
    for (int ht = 0; ht < 4; ++ht)
#pragma unroll
        for (int m = 0; m < 2; ++m){
            bh[ht][m].u = *(const uint4*)(BUFA + row64_chunk(64*wid + 16*ht + hl, 4*m + G));
            bl[ht][m].u = *(const uint4*)(BUFB + row64_chunk(64*wid + 16*ht + hl, 4*m + G));
        }

    f32x4 yacc[4][4];
#pragma unroll
    for (int ot = 0; ot < 4; ++ot)
#pragma unroll
        for (int ht = 0; ht < 4; ++ht) yacc[ot][ht] = (f32x4){0.f,0.f,0.f,0.f};
#pragma unroll
    for (int ot = 0; ot < 4; ++ot)
#pragma unroll
        for (int m = 0; m < 2; ++m){
            U4S8 wf = wfrag_f(Wf, hl, G, ot, m);
#pragma unroll
            for (int ht = 0; ht < 4; ++ht){
                yacc[ot][ht] = __builtin_amdgcn_mfma_f32_16x16x32_bf16(wf.s, bh[ht][m].s, yacc[ot][ht], 0,0,0);
                yacc[ot][ht] = __builtin_amdgcn_mfma_f32_16x16x32_bf16(wf.s, bl[ht][m].s, yacc[ot][ht], 0,0,0);
            }
        }
    float bfv[4][4];
#pragma unroll
    for (int ot = 0; ot < 4; ++ot)
#pragma unroll
        for (int r = 0; r < 4; ++r) bfv[ot][r] = bfc[16*ot + 4*G + r];
#pragma unroll
    for (int ot = 0; ot < 4; ++ot)
#pragma unroll
        for (int ht = 0; ht < 4; ++ht)
#pragma unroll
            for (int r = 0; r < 4; ++r){
                int o = 16*ot + 4*G + r;
                int h = 64*wid + 16*ht + hl;
                float y = fmaxf(yacc[ot][ht][r] + bfv[ot][r], 0.f);
                out[base_bd + (long)o*CSTRIDE + (long)h*NW] = y;
            }
}

extern "C" void kernel_launch(void* const* d_in, const int* in_sizes, int n_in,
                              void* d_out, int out_size, void* d_ws, size_t ws_size,
                              hipStream_t stream) {
    (void)in_sizes; (void)n_in; (void)out_size;
    const float* rep = (const float*)d_in[0];
    const float* Wq  = (const float*)d_in[1];
    const float* bq  = (const float*)d_in[2];
    const float* Wk  = (const float*)d_in[3];
    const float* bk  = (const float*)d_in[4];
    const float* Wv  = (const float*)d_in[5];
    const float* bv  = (const float*)d_in[6];
    const float* Wf  = (const float*)d_in[7];
    const float* bfc = (const float*)d_in[8];
    float* out = (float*)d_out;

    if (ws_size >= WS_NEED) {
        ushort_t* qws = (ushort_t*)d_ws;
        ushort_t* kws = qws + QSZ_ELEMS;
        ushort_t* vws = kws + QSZ_ELEMS;
        k1_proj<<<dim3(1536), dim3(256), 0, stream>>>(rep, Wq, bq, Wk, bk, Wv, bv, qws, kws, vws);
        k2_attn<<<dim3(1536), dim3(256), 0, stream>>>(qws, kws, vws);
        k3_fc  <<<dim3(1536), dim3(256), 0, stream>>>(qws, Wf, bfc, out);
    } else {
        sa_mfma<<<dim3(1536), dim3(256), 0, stream>>>(rep, Wq, bq, Wk, bk, Wv, bv, Wf, bfc, out);
    }
}

// Round 7
// 174.572 us; speedup vs baseline: 1.4888x; 1.4888x over previous
//
#include <hip/hip_runtime.h>

typedef float f32x4 __attribute__((ext_vector_type(4)));
typedef short bf16x8 __attribute__((ext_vector_type(8)));
typedef unsigned short ushort_t;

#define NB 2
#define NC 64
#define ND 12
#define NH 256
#define NW 64
#define CSTRIDE (ND*NH*NW)   // 196608
#define QSZ_ELEMS (24*64*256*64)          // 25,165,824 bf16 elems per tensor
#define WS_NEED   ((size_t)3*QSZ_ELEMS*2) // 150,994,944 bytes

__device__ __forceinline__ ushort_t bf_round(float f){
    unsigned int u = __float_as_uint(f);
    return (ushort_t)((u + 0x7fffu + ((u >> 16) & 1u)) >> 16);   // RNE
}
__device__ __forceinline__ float bf_to_f(ushort_t s){ return __uint_as_float(((unsigned int)s) << 16); }

union U4S8 { uint4 u; bf16x8 s; };

// swizzled byte offsets: [R][64]-bf16 row-major, 8-elem (16B) chunks, chunk ^= row&7
__device__ __forceinline__ int row64_off(int r, int o){
    return r*128 + ((((o>>3) ^ (r&7)))<<4) + (o&7)*2;
}
__device__ __forceinline__ int row64_chunk(int r, int kchunk){
    return r*128 + (((kchunk ^ (r&7)))<<4);
}
// Vt: [64 c][256 g] bf16, rowbytes 512, 32 chunks, chunk ^= c&7
__device__ __forceinline__ int vt_off(int c, int g){
    return c*512 + ((((g>>3) ^ (c&7)))<<4) + (g&7)*2;
}
__device__ __forceinline__ int vt_chunk(int c, int gchunk){
    return c*512 + (((gchunk ^ (c&7)))<<4);
}

// weight frag: lane (hl,G) holds W[hl+16*ot][32m+8G .. +8] as bf16x8
__device__ __forceinline__ U4S8 wfrag_f(const float* W, int hl, int G, int ot, int m){
    const float* p2 = W + (hl + 16*ot)*NC + 32*m + 8*G;
    float4 f0 = *(const float4*)p2;
    float4 f1 = *(const float4*)(p2 + 4);
    U4S8 u; ushort_t* s = (ushort_t*)&u;
    s[0]=bf_round(f0.x); s[1]=bf_round(f0.y); s[2]=bf_round(f0.z); s[3]=bf_round(f0.w);
    s[4]=bf_round(f1.x); s[5]=bf_round(f1.y); s[6]=bf_round(f1.z); s[7]=bf_round(f1.w);
    return u;
}

// ===================== Kernel 1 (v5): QKV projection, 32KB LDS, no VGPR cap ==============
// block = (bd, h-tile of 4) covering all 64 w. Local row n = hh*64 + w (hh=n>>6).
// Round-4 proven data path; XL reused as bounce buffer (32 KB LDS -> 5 blocks/CU by LDS).
// launch_bounds min-waves kept at 2: (256,4) in round 6 clamped VGPR to 64 and spilled
// acc[4][4] (FETCH +144MB, WRITE +180MB scratch). With ~108 VGPR the HW still gives
// 4 waves/SIMD (108 <= 128) -> 4 blocks/CU, occupancy doubles vs round 4 WITHOUT spills.
__global__ __launch_bounds__(256, 2) void k1_proj(
    const float* __restrict__ rep,
    const float* __restrict__ Wq, const float* __restrict__ bq,
    const float* __restrict__ Wk, const float* __restrict__ bk,
    const float* __restrict__ Wv, const float* __restrict__ bv,
    ushort_t* __restrict__ qws, ushort_t* __restrict__ kws, ushort_t* __restrict__ vws)
{
    __shared__ __align__(16) unsigned char XL[32768];   // X stage, then output bounce

    const int t = threadIdx.x, lane = t & 63, wid = t >> 6;
    const int G = lane >> 4, hl = lane & 15;
    const int blk = blockIdx.x;
    const int bd = blk >> 6;
    const int h0 = (blk & 63) * 4;
    const int d = bd % ND, b = bd / ND;
    const long dbase2 = (long)b*NC*CSTRIDE + (long)d*(NH*NW) + (long)h0*NW; // + c*CSTRIDE + n

    // ---- stage X tile: fully coalesced (per instr: 256 consecutive floats per c) ----
#pragma unroll
    for (int oct = 0; oct < 8; ++oct){
        float f[8];
#pragma unroll
        for (int j = 0; j < 8; ++j)
            f[j] = rep[dbase2 + (long)(8*oct + j)*CSTRIDE + t];
        U4S8 u; ushort_t* s = (ushort_t*)&u;
#pragma unroll
        for (int j = 0; j < 8; ++j) s[j] = bf_round(f[j]);
        *(uint4*)(XL + row64_chunk(t, oct)) = u.u;
    }
    __syncthreads();

    U4S8 xa[4][2];
#pragma unroll
    for (int nt = 0; nt < 4; ++nt)
#pragma unroll
        for (int m = 0; m < 2; ++m)
            xa[nt][m].u = *(const uint4*)(XL + row64_chunk(64*wid + 16*nt + hl, 4*m + G));
    __syncthreads();   // all waves done reading X -> XL free for bounce

    auto pass = [&](const float* W, const float* bias, float scale, ushort_t* dst){
        U4S8 bw[4][2];
        float bb[4];
#pragma unroll
        for (int ot = 0; ot < 4; ++ot){
            bw[ot][0] = wfrag_f(W, hl, G, ot, 0);
            bw[ot][1] = wfrag_f(W, hl, G, ot, 1);
            bb[ot] = bias[hl + 16*ot];
        }
        f32x4 acc[4][4];
#pragma unroll
        for (int nt = 0; nt < 4; ++nt)
#pragma unroll
            for (int ot = 0; ot < 4; ++ot){
                f32x4 a = {0.f,0.f,0.f,0.f};
                a = __builtin_amdgcn_mfma_f32_16x16x32_bf16(xa[nt][0].s, bw[ot][0].s, a, 0,0,0);
                a = __builtin_amdgcn_mfma_f32_16x16x32_bf16(xa[nt][1].s, bw[ot][1].s, a, 0,0,0);
#pragma unroll
                for (int r = 0; r < 4; ++r) a[r] = fmaxf(a[r] + bb[ot], 0.f) * scale;
                acc[nt][ot] = a;
            }
        // scatter D[n,o] -> bounce LDS
#pragma unroll
        for (int nt = 0; nt < 4; ++nt)
#pragma unroll
            for (int ot = 0; ot < 4; ++ot)
#pragma unroll
                for (int r = 0; r < 4; ++r){
                    int n = 64*wid + 16*nt + 4*G + r;
                    int o = hl + 16*ot;
                    *(ushort_t*)(XL + row64_off(n, o)) = bf_round(acc[nt][ot][r]);
                }
        __syncthreads();
        // full-line ws writes: chunk (n, c8); ws row = (bd*64 + w)*256 + h0 + hh
#pragma unroll
        for (int i = 0; i < 8; ++i){
            int g2 = i*256 + t; int n = g2 >> 3; int c8 = g2 & 7;
            uint4 u = *(const uint4*)(XL + row64_chunk(n, c8));
            long row_g = ((long)bd*64 + (n & 63))*256 + h0 + (n >> 6);
            *(uint4*)((unsigned char*)dst + row_g*128 + c8*16) = u;
        }
        __syncthreads();   // before next pass overwrites the bounce
    };
    pass(Wq, bq, 0.125f, qws);   // fold 1/sqrt(C)
    pass(Wk, bk, 1.0f,   kws);
    pass(Wv, bv, 1.0f,   vws);
}

// ===================== Kernel 2: attention per (bd,w), coalesced ws I/O =====================
__global__ __launch_bounds__(256, 2) void k2_attn(
    ushort_t* __restrict__ qws, const ushort_t* __restrict__ kws, const ushort_t* __restrict__ vws)
{
    __shared__ __align__(16) unsigned char smem[65536];
    unsigned char* KL = smem;          // K [256 g][64 c] row64 -> later O-bounce [h][c]
    unsigned char* VT = smem + 32768;  // Vt [64 c][256 g]

    const int t = threadIdx.x, lane = t & 63, wid = t >> 6;
    const int G = lane >> 4, hl = lane & 15;
    const int bdw = blockIdx.x;
    ushort_t* qslice = qws + (size_t)bdw*16384;          // [h][c], also O dst
    const unsigned char* kslice = (const unsigned char*)(kws + (size_t)bdw*16384);
    const unsigned char* vslice = (const unsigned char*)(vws + (size_t)bdw*16384);

    // ---- stage K (b128 direct) and V (transpose scatter) ----
#pragma unroll
    for (int i = 0; i < 8; ++i){
        int g2 = i*256 + t; int g = g2 >> 3; int c8 = g2 & 7;
        uint4 ku = *(const uint4*)(kslice + g2*16);
        *(uint4*)(KL + row64_chunk(g, c8)) = ku;
        U4S8 vu; vu.u = *(const uint4*)(vslice + g2*16);
#pragma unroll
        for (int j = 0; j < 8; ++j)
            *(ushort_t*)(VT + vt_off(8*c8 + j, g)) = (ushort_t)vu.s[j];
    }
    __syncthreads();

    // Q B-frags direct from global (plain [h][c] rows, octet 4m+G at byte (4m+G)*16)
    U4S8 qfr[4][2];
#pragma unroll
    for (int ht = 0; ht < 4; ++ht)
#pragma unroll
        for (int m = 0; m < 2; ++m)
            qfr[ht][m].u = *(const uint4*)((const unsigned char*)qslice
                              + (64*wid + 16*ht + hl)*128 + (4*m + G)*16);

    // ================= flash attention over g-tiles of 64 ================
    f32x4 oacc[4][4];
#pragma unroll
    for (int ct = 0; ct < 4; ++ct)
#pragma unroll
        for (int ht = 0; ht < 4; ++ht) oacc[ct][ht] = (f32x4){0.f,0.f,0.f,0.f};
    float m_run[4], l_run[4];
#pragma unroll
    for (int ht = 0; ht < 4; ++ht){ m_run[ht] = -1e30f; l_run[ht] = 0.f; }

    const int srcq0 = (16*((2*G    ) & 3) + hl)*4;
    const int srcq1 = (16*((2*G + 1) & 3) + hl)*4;

    for (int gb = 0; gb < NH; gb += 64){
        U4S8 kfr[4][2];
#pragma unroll
        for (int gt = 0; gt < 4; ++gt)
#pragma unroll
            for (int m = 0; m < 2; ++m)
                kfr[gt][m].u = *(const uint4*)(KL + row64_chunk(gb + 16*gt + hl, 4*m + G));

        f32x4 sacc[4][4];
#pragma unroll
        for (int gt = 0; gt < 4; ++gt)
#pragma unroll
            for (int ht = 0; ht < 4; ++ht){
                f32x4 a = {0.f,0.f,0.f,0.f};
                a = __builtin_amdgcn_mfma_f32_16x16x32_bf16(kfr[gt][0].s, qfr[ht][0].s, a, 0,0,0);
                a = __builtin_amdgcn_mfma_f32_16x16x32_bf16(kfr[gt][1].s, qfr[ht][1].s, a, 0,0,0);
                sacc[gt][ht] = a;
            }

        unsigned int pk[4][4][2];
#pragma unroll
        for (int ht = 0; ht < 4; ++ht){
            float cm = -1e30f;
#pragma unroll
            for (int gt = 0; gt < 4; ++gt)
#pragma unroll
                for (int r = 0; r < 4; ++r) cm = fmaxf(cm, sacc[gt][ht][r]);
            cm = fmaxf(cm, __shfl_xor(cm, 16));
            cm = fmaxf(cm, __shfl_xor(cm, 32));
            const float mn  = fmaxf(m_run[ht], cm);
            const float corr = __expf(m_run[ht] - mn);
            m_run[ht] = mn;
            float ls = 0.f;
#pragma unroll
            for (int gt = 0; gt < 4; ++gt){
                f32x4 s = sacc[gt][ht];
                float e0 = __expf(s[0]-mn), e1 = __expf(s[1]-mn);
                float e2 = __expf(s[2]-mn), e3 = __expf(s[3]-mn);
                ls += (e0+e1)+(e2+e3);
                pk[ht][gt][0] = (unsigned int)bf_round(e0) | ((unsigned int)bf_round(e1) << 16);
                pk[ht][gt][1] = (unsigned int)bf_round(e2) | ((unsigned int)bf_round(e3) << 16);
            }
            ls += __shfl_xor(ls, 16);
            ls += __shfl_xor(ls, 32);
            l_run[ht] = l_run[ht]*corr + ls;
#pragma unroll
            for (int ct = 0; ct < 4; ++ct)
#pragma unroll
                for (int r = 0; r < 4; ++r) oacc[ct][ht][r] *= corr;
        }

        U4S8 vfr[4][2];
#pragma unroll
        for (int ct = 0; ct < 4; ++ct)
#pragma unroll
            for (int m = 0; m < 2; ++m)
                vfr[ct][m].u = *(const uint4*)(VT + vt_chunk(16*ct + hl, (gb>>3) + 4*m + G));

#pragma unroll
        for (int m = 0; m < 2; ++m){
            U4S8 bfr[4];
#pragma unroll
            for (int ht = 0; ht < 4; ++ht){
                unsigned int wv[4];
#pragma unroll
                for (int jj = 0; jj < 4; ++jj){
                    const int src = (jj >> 1) ? srcq1 : srcq0;
                    const int p2  = jj & 1;
                    int rA = __builtin_amdgcn_ds_bpermute(src, (int)pk[ht][2*m  ][p2]);
                    int rB = __builtin_amdgcn_ds_bpermute(src, (int)pk[ht][2*m+1][p2]);
                    wv[jj] = (lane < 32) ? (unsigned int)rA : (unsigned int)rB;
                }
                bfr[ht].u = make_uint4(wv[0], wv[1], wv[2], wv[3]);
            }
#pragma unroll
            for (int ct = 0; ct < 4; ++ct)
#pragma unroll
                for (int ht = 0; ht < 4; ++ht)
                    oacc[ct][ht] = __builtin_amdgcn_mfma_f32_16x16x32_bf16(vfr[ct][m].s, bfr[ht].s, oacc[ct][ht], 0,0,0);
        }
    }

    // ---- epilogue: normalize, bounce O[h][c] through KL, coalesced write to qslice ----
    float invl[4];
#pragma unroll
    for (int ht = 0; ht < 4; ++ht) invl[ht] = 1.f / l_run[ht];

    __syncthreads();   // all waves done with KL/VT
#pragma unroll
    for (int ct = 0; ct < 4; ++ct)
#pragma unroll
        for (int ht = 0; ht < 4; ++ht)
#pragma unroll
            for (int r = 0; r < 4; ++r){
                int h = 64*wid + 16*ht + hl;
                int c = 16*ct + 4*G + r;
                *(ushort_t*)(KL + row64_off(h, c)) = bf_round(oacc[ct][ht][r] * invl[ht]);
            }
    __syncthreads();
#pragma unroll
    for (int i = 0; i < 8; ++i){
        int g2 = i*256 + t;
        uint4 u = *(const uint4*)(KL + row64_chunk(g2 >> 3, g2 & 7));
        *(uint4*)((unsigned char*)qslice + g2*16) = u;
    }
}

// ===================== Kernel 3: FC + ReLU + transpose-out, coalesced =====================
__global__ __launch_bounds__(256, 2) void k3_fc(
    const ushort_t* __restrict__ ows, const float* __restrict__ Wf, const float* __restrict__ bfc,
    float* __restrict__ out)
{
    __shared__ __align__(16) float YL[16384];   // [256 n][64 o], o swizzled, 64 KB

    const int t = threadIdx.x, lane = t & 63, wid = t >> 6;
    const int G = lane >> 4, hl = lane & 15;
    const int blk = blockIdx.x;
    const int bd = blk >> 6;
    const int h0 = (blk & 63) * 4;
    const int d = bd % ND, b = bd / ND;

    // A-frags: O rows (w = 16nt+hl, h = h0+wid), octet 4m+G
    U4S8 xa[4][2];
#pragma unroll
    for (int nt = 0; nt < 4; ++nt)
#pragma unroll
        for (int m = 0; m < 2; ++m){
            long row_g = ((long)bd*64 + (16*nt + hl))*256 + h0 + wid;
            xa[nt][m].u = *(const uint4*)((const unsigned char*)ows + row_g*128 + (4*m + G)*16);
        }

    U4S8 bw[4][2];
    float bb[4];
#pragma unroll
    for (int ot = 0; ot < 4; ++ot){
        bw[ot][0] = wfrag_f(Wf, hl, G, ot, 0);
        bw[ot][1] = wfrag_f(Wf, hl, G, ot, 1);
        bb[ot] = bfc[hl + 16*ot];
    }

    f32x4 acc[4][4];
#pragma unroll
    for (int nt = 0; nt < 4; ++nt)
#pragma unroll
        for (int ot = 0; ot < 4; ++ot){
            f32x4 a = {0.f,0.f,0.f,0.f};
            a = __builtin_amdgcn_mfma_f32_16x16x32_bf16(xa[nt][0].s, bw[ot][0].s, a, 0,0,0);
            a = __builtin_amdgcn_mfma_f32_16x16x32_bf16(xa[nt][1].s, bw[ot][1].s, a, 0,0,0);
#pragma unroll
            for (int r = 0; r < 4; ++r) a[r] = fmaxf(a[r] + bb[ot], 0.f);
            acc[nt][ot] = a;
        }

    // scatter Y[n][o] -> LDS (o ^= (n>>2)&31 swizzle)
#pragma unroll
    for (int nt = 0; nt < 4; ++nt)
#pragma unroll
        for (int ot = 0; ot < 4; ++ot)
#pragma unroll
            for (int r = 0; r < 4; ++r){
                int n = 64*wid + 16*nt + 4*G + r;
                int o = hl + 16*ot;
                YL[(n<<6) + (o ^ ((n>>2)&31))] = acc[nt][ot][r];
            }
    __syncthreads();

    // coalesced out writes: per instr one o, 1KB contiguous (4h x 64w)
    const long base3 = (long)b*NC*CSTRIDE + (long)d*(NH*NW) + (long)h0*NW;
#pragma unroll
    for (int i = 0; i < 16; ++i){
        int idx = i*1024 + t*4;
        int o = idx >> 8;
        int n0 = idx & 255;
        int osw = o ^ (t & 31);
        float4 v;
        v.x = YL[((n0+0)<<6) + osw];
        v.y = YL[((n0+1)<<6) + osw];
        v.z = YL[((n0+2)<<6) + osw];
        v.w = YL[((n0+3)<<6) + osw];
        *(float4*)(&out[base3 + (long)o*CSTRIDE + n0]) = v;
    }
}

// ===================== Fallback: round-3 fused kernel (proven) =====================
__global__ __launch_bounds__(256, 2) void sa_mfma(
    const float* __restrict__ rep,
    const float* __restrict__ Wq, const float* __restrict__ bq,
    const float* __restrict__ Wk, const float* __restrict__ bk,
    const float* __restrict__ Wv, const float* __restrict__ bv,
    const float* __restrict__ Wf, const float* __restrict__ bfc,
    float* __restrict__ out)
{
    __shared__ __align__(16) unsigned char smem[65536];
    unsigned char* BUFA = smem;
    unsigned char* BUFB = smem + 32768;

    const int t = threadIdx.x, lane = t & 63, wid = t >> 6;
    const int G = lane >> 4, hl = lane & 15;
    const int j = blockIdx.x;
    const int x = j & 7;
    const int p = j >> 3;
    const int group = ((p >> 6) << 3) + x;
    const int w = p & 63;
    const int d = group % ND;
    const int b = group / ND;
    const long base_bd = (long)b*(NC*CSTRIDE) + (long)d*(NH*NW) + w;

    {
        const int h = t;
        const long rbase = base_bd + (long)h*NW;
#pragma unroll
        for (int c8 = 0; c8 < 8; ++c8){
            U4S8 u;
            ushort_t* s = (ushort_t*)&u;
#pragma unroll
            for (int jj = 0; jj < 8; ++jj)
                s[jj] = bf_round(rep[rbase + (long)(c8*8 + jj)*CSTRIDE]);
            *(uint4*)(BUFB + row64_chunk(h, c8)) = u.u;
        }
    }
    U4S8 xafr[4][2];
#pragma unroll
    for (int ht = 0; ht < 4; ++ht)
#pragma unroll
        for (int m = 0; m < 2; ++m)
            xafr[ht][m].u = *(const uint4*)(BUFB + row64_chunk(64*wid + 16*ht + hl, 4*m + G));

    auto do_proj = [&](const float* W, const float* bias, float scale, f32x4 (&acc)[4][4]){
        U4S8 bw[4][2];
#pragma unroll
        for (int ot = 0; ot < 4; ++ot){ bw[ot][0] = wfrag_f(W, hl, G, ot, 0); bw[ot][1] = wfrag_f(W, hl, G, ot, 1); }
        float bb[4];
#pragma unroll
        for (int ot = 0; ot < 4; ++ot) bb[ot] = bias[hl + 16*ot];
#pragma unroll
        for (int ht = 0; ht < 4; ++ht)
#pragma unroll
            for (int ot = 0; ot < 4; ++ot){
                f32x4 a = {0.f, 0.f, 0.f, 0.f};
                a = __builtin_amdgcn_mfma_f32_16x16x32_bf16(xafr[ht][0].s, bw[ot][0].s, a, 0, 0, 0);
                a = __builtin_amdgcn_mfma_f32_16x16x32_bf16(xafr[ht][1].s, bw[ot][1].s, a, 0, 0, 0);
#pragma unroll
                for (int r = 0; r < 4; ++r) a[r] = fmaxf(a[r] + bb[ot], 0.f) * scale;
                acc[ht][ot] = a;
            }
    };

    {
        f32x4 qa[4][4];
        do_proj(Wq, bq, 0.125f, qa);
#pragma unroll
        for (int ht = 0; ht < 4; ++ht)
#pragma unroll
            for (int ot = 0; ot < 4; ++ot)
#pragma unroll
                for (int r = 0; r < 4; ++r){
                    int h = 64*wid + 16*ht + 4*G + r;
                    int o = hl + 16*ot;
                    *(ushort_t*)(BUFA + row64_off(h, o)) = bf_round(qa[ht][ot][r]);
                }
    }
    U4S8 qfr[4][2];
#pragma unroll
    for (int ht = 0; ht < 4; ++ht)
#pragma unroll
        for (int m = 0; m < 2; ++m)
            qfr[ht][m].u = *(const uint4*)(BUFA + row64_chunk(64*wid + 16*ht + hl, 4*m + G));

    {
        f32x4 ka[4][4];
        do_proj(Wk, bk, 1.0f, ka);
#pragma unroll
        for (int gt = 0; gt < 4; ++gt)
#pragma unroll
            for (int ot = 0; ot < 4; ++ot)
#pragma unroll
                for (int r = 0; r < 4; ++r){
                    int g = 64*wid + 16*gt + 4*G + r;
                    int o = hl + 16*ot;
                    *(ushort_t*)(BUFA + row64_off(g, o)) = bf_round(ka[gt][ot][r]);
                }
    }
    f32x4 va[4][4];
    do_proj(Wv, bv, 1.0f, va);
    __syncthreads();
#pragma unroll
    for (int gt = 0; gt < 4; ++gt)
#pragma unroll
        for (int ot = 0; ot < 4; ++ot)
#pragma unroll
            for (int r = 0; r < 4; ++r){
                int g = 64*wid + 16*gt + 4*G + r;
                int c = hl + 16*ot;
                *(ushort_t*)(BUFB + vt_off(c, g)) = bf_round(va[gt][ot][r]);
            }
    __syncthreads();

    f32x4 oacc[4][4];
#pragma unroll
    for (int ct = 0; ct < 4; ++ct)
#pragma unroll
        for (int ht = 0; ht < 4; ++ht) oacc[ct][ht] = (f32x4){0.f,0.f,0.f,0.f};
    float m_run[4], l_run[4];
#pragma unroll
    for (int ht = 0; ht < 4; ++ht){ m_run[ht] = -1e30f; l_run[ht] = 0.f; }

    const int srcq0 = (16*((2*G    ) & 3) + hl)*4;
    const int srcq1 = (16*((2*G + 1) & 3) + hl)*4;

    for (int gb = 0; gb < NH; gb += 64){
        U4S8 kfr[4][2];
#pragma unroll
        for (int gt = 0; gt < 4; ++gt)
#pragma unroll
            for (int m = 0; m < 2; ++m)
                kfr[gt][m].u = *(const uint4*)(BUFA + row64_chunk(gb + 16*gt + hl, 4*m + G));

        f32x4 sacc[4][4];
#pragma unroll
        for (int gt = 0; gt < 4; ++gt)
#pragma unroll
            for (int ht = 0; ht < 4; ++ht){
                f32x4 a = {0.f,0.f,0.f,0.f};
                a = __builtin_amdgcn_mfma_f32_16x16x32_bf16(kfr[gt][0].s, qfr[ht][0].s, a, 0,0,0);
                a = __builtin_amdgcn_mfma_f32_16x16x32_bf16(kfr[gt][1].s, qfr[ht][1].s, a, 0,0,0);
                sacc[gt][ht] = a;
            }

        unsigned int pk[4][4][2];
#pragma unroll
        for (int ht = 0; ht < 4; ++ht){
            float cm = -1e30f;
#pragma unroll
            for (int gt = 0; gt < 4; ++gt)
#pragma unroll
                for (int r = 0; r < 4; ++r) cm = fmaxf(cm, sacc[gt][ht][r]);
            cm = fmaxf(cm, __shfl_xor(cm, 16));
            cm = fmaxf(cm, __shfl_xor(cm, 32));
            const float mn  = fmaxf(m_run[ht], cm);
            const float corr = __expf(m_run[ht] - mn);
            m_run[ht] = mn;
            float ls = 0.f;
#pragma unroll
            for (int gt = 0; gt < 4; ++gt){
                f32x4 s = sacc[gt][ht];
                float e0 = __expf(s[0]-mn), e1 = __expf(s[1]-mn);
                float e2 = __expf(s[2]-mn), e3 = __expf(s[3]-mn);
                ls += (e0+e1)+(e2+e3);
                pk[ht][gt][0] = (unsigned int)bf_round(e0) | ((unsigned int)bf_round(e1) << 16);
                pk[ht][gt][1] = (unsigned int)bf_round(e2) | ((unsigned int)bf_round(e3) << 16);
            }
            ls += __shfl_xor(ls, 16);
            ls += __shfl_xor(ls, 32);
            l_run[ht] = l_run[ht]*corr + ls;
#pragma unroll
            for (int ct = 0; ct < 4; ++ct)
#pragma unroll
                for (int r = 0; r < 4; ++r) oacc[ct][ht][r] *= corr;
        }

        U4S8 vfr[4][2];
#pragma unroll
        for (int ct = 0; ct < 4; ++ct)
#pragma unroll
            for (int m = 0; m < 2; ++m)
                vfr[ct][m].u = *(const uint4*)(BUFB + vt_chunk(16*ct + hl, (gb>>3) + 4*m + G));

#pragma unroll
        for (int m = 0; m < 2; ++m){
            U4S8 bfr[4];
#pragma unroll
            for (int ht = 0; ht < 4; ++ht){
                unsigned int wv[4];
#pragma unroll
                for (int jj = 0; jj < 4; ++jj){
                    const int src = (jj >> 1) ? srcq1 : srcq0;
                    const int p2  = jj & 1;
                    int rA = __builtin_amdgcn_ds_bpermute(src, (int)pk[ht][2*m  ][p2]);
                    int rB = __builtin_amdgcn_ds_bpermute(src, (int)pk[ht][2*m+1][p2]);
                    wv[jj] = (lane < 32) ? (unsigned int)rA : (unsigned int)rB;
                }
                bfr[ht].u = make_uint4(wv[0], wv[1], wv[2], wv[3]);
            }
#pragma unroll
            for (int ct = 0; ct < 4; ++ct)
#pragma unroll
                for (int ht = 0; ht < 4; ++ht)
                    oacc[ct][ht] = __builtin_amdgcn_mfma_f32_16x16x32_bf16(vfr[ct][m].s, bfr[ht].s, oacc[ct][ht], 0,0,0);
        }
    }

    float invl[4];
#pragma unroll
    for (int ht = 0; ht < 4; ++ht) invl[ht] = 1.f / l_run[ht];
    __syncthreads();
#pragma unroll
    for (int ct = 0; ct < 4; ++ct)
#pragma unroll
        for (int ht = 0; ht < 4; ++ht)
#pragma unroll
            for (int r = 0; r < 4; ++r){
                float v = oacc[ct][ht][r] * invl[ht];
                ushort_t hi = bf_round(v);
                ushort_t lo = bf_round(v - bf_to_f(hi));
                int hrow = 64*wid + 16*ht + hl;
                int c = 16*ct + 4*G + r;
                *(ushort_t*)(BUFA + row64_off(hrow, c)) = hi;
                *(ushort_t*)(BUFB + row64_off(hrow, c)) = lo;
            }
    U4S8 bh[4][2], bl[4][2];
#pragma unroll
    for (int ht = 0; ht < 4; ++ht)
#pragma unroll
        for (int m = 0; m < 2; ++m){
            bh[ht][m].u = *(const uint4*)(BUFA + row64_chunk(64*wid + 16*ht + hl, 4*m + G));
            bl[ht][m].u = *(const uint4*)(BUFB + row64_chunk(64*wid + 16*ht + hl, 4*m + G));
        }

    f32x4 yacc[4][4];
#pragma unroll
    for (int ot = 0; ot < 4; ++ot)
#pragma unroll
        for (int ht = 0; ht < 4; ++ht) yacc[ot][ht] = (f32x4){0.f,0.f,0.f,0.f};
#pragma unroll
    for (int ot = 0; ot < 4; ++ot)
#pragma unroll
        for (int m = 0; m < 2; ++m){
            U4S8 wf = wfrag_f(Wf, hl, G, ot, m);
#pragma unroll
            for (int ht = 0; ht < 4; ++ht){
                yacc[ot][ht] = __builtin_amdgcn_mfma_f32_16x16x32_bf16(wf.s, bh[ht][m].s, yacc[ot][ht], 0,0,0);
                yacc[ot][ht] = __builtin_amdgcn_mfma_f32_16x16x32_bf16(wf.s, bl[ht][m].s, yacc[ot][ht], 0,0,0);
            }
        }
    float bfv[4][4];
#pragma unroll
    for (int ot = 0; ot < 4; ++ot)
#pragma unroll
        for (int r = 0; r < 4; ++r) bfv[ot][r] = bfc[16*ot + 4*G + r];
#pragma unroll
    for (int ot = 0; ot < 4; ++ot)
#pragma unroll
        for (int ht = 0; ht < 4; ++ht)
#pragma unroll
            for (int r = 0; r < 4; ++r){
                int o = 16*ot + 4*G + r;
                int h = 64*wid + 16*ht + hl;
                float y = fmaxf(yacc[ot][ht][r] + bfv[ot][r], 0.f);
                out[base_bd + (long)o*CSTRIDE + (long)h*NW] = y;
            }
}

extern "C" void kernel_launch(void* const* d_in, const int* in_sizes, int n_in,
                              void* d_out, int out_size, void* d_ws, size_t ws_size,
                              hipStream_t stream) {
    (void)in_sizes; (void)n_in; (void)out_size;
    const float* rep = (const float*)d_in[0];
    const float* Wq  = (const float*)d_in[1];
    const float* bq  = (const float*)d_in[2];
    const float* Wk  = (const float*)d_in[3];
    const float* bk  = (const float*)d_in[4];
    const float* Wv  = (const float*)d_in[5];
    const float* bv  = (const float*)d_in[6];
    const float* Wf  = (const float*)d_in[7];
    const float* bfc = (const float*)d_in[8];
    float* out = (float*)d_out;

    if (ws_size >= WS_NEED) {
        ushort_t* qws = (ushort_t*)d_ws;
        ushort_t* kws = qws + QSZ_ELEMS;
        ushort_t* vws = kws + QSZ_ELEMS;
        k1_proj<<<dim3(1536), dim3(256), 0, stream>>>(rep, Wq, bq, Wk, bk, Wv, bv, qws, kws, vws);
        k2_attn<<<dim3(1536), dim3(256), 0, stream>>>(qws, kws, vws);
        k3_fc  <<<dim3(1536), dim3(256), 0, stream>>>(qws, Wf, bfc, out);
    } else {
        sa_mfma<<<dim3(1536), dim3(256), 0, stream>>>(rep, Wq, bq, Wk, bk, Wv, bv, Wf, bfc, out);
    }
}